// Round 1
// baseline (110.854 us; speedup 1.0000x reference)
//
#include <hip/hip_runtime.h>

// Problem constants (from setup_inputs): x (8, 8192, 512) f32, W (512,128) f32, perm (128,) f32
#define B_ 8
#define N_ 8192
#define D_ 512
#define R_ 128

// Kernel 1: per-chunk column sums of x over the sequence axis.
// grid = B_*chunks blocks, 512 threads. Threads 0..127 cover d in float4 quads,
// 4 row-parallel groups (rp) combined through LDS at the end.
__global__ __launch_bounds__(512) void k_reduce(const float* __restrict__ x,
                                                float* __restrict__ partials,
                                                int chunks) {
    const int rows  = N_ / chunks;          // rows per chunk
    const int b     = blockIdx.x / chunks;
    const int chunk = blockIdx.x % chunks;
    const int t  = threadIdx.x;
    const int dq = t & 127;                 // d-quad index: d = dq*4 .. dq*4+3
    const int rp = t >> 7;                  // row-parallel group 0..3

    const float4* x4 = reinterpret_cast<const float4*>(x)
                       + ((size_t)b * N_ + (size_t)chunk * rows) * (D_ / 4);

    float4 acc = make_float4(0.f, 0.f, 0.f, 0.f);
    for (int n = rp; n < rows; n += 4) {
        float4 v = x4[(size_t)n * (D_ / 4) + dq];
        acc.x += v.x; acc.y += v.y; acc.z += v.z; acc.w += v.w;
    }

    __shared__ float4 s[512];
    s[t] = acc;
    __syncthreads();
    if (rp == 0) {
        float4 a1 = s[dq + 128], a2 = s[dq + 256], a3 = s[dq + 384];
        float4 r;
        r.x = (acc.x + a1.x) + (a2.x + a3.x);
        r.y = (acc.y + a1.y) + (a2.y + a3.y);
        r.z = (acc.z + a1.z) + (a2.z + a3.z);
        r.w = (acc.w + a1.w) + (a2.w + a3.w);
        reinterpret_cast<float4*>(partials)[(size_t)(b * chunks + chunk) * 128 + dq] = r;
    }
}

// Kernel 2: reduce chunk partials -> xbar (mean), project through W, scale by perm.
// grid = B_ blocks, 128 threads (one per output channel r).
__global__ __launch_bounds__(128) void k_proj(const float* __restrict__ partials,
                                              const float* __restrict__ W,
                                              const float* __restrict__ perm,
                                              float* __restrict__ y,
                                              int chunks) {
    const int b = blockIdx.x;
    const int t = threadIdx.x;      // 0..127
    __shared__ float xbar[D_];

    for (int j = 0; j < D_ / 128; ++j) {
        const int d = t + 128 * j;
        float s = 0.f;
        for (int c = 0; c < chunks; ++c)
            s += partials[((size_t)(b * chunks + c)) * D_ + d];
        xbar[d] = s * (1.0f / (float)N_);
    }
    __syncthreads();

    float acc = 0.f;
    #pragma unroll 8
    for (int d = 0; d < D_; ++d)
        acc = fmaf(xbar[d], W[(size_t)d * R_ + t], acc);
    y[b * R_ + t] = acc * perm[t];
}

// Kernel 3: broadcast y[b, :] to out[b, n, :] for all n. Coalesced float4 stores.
// grid = B_ * (N_/64) = 1024 blocks, 256 threads; each block writes 64 rows.
__global__ __launch_bounds__(256) void k_bcast(const float* __restrict__ y,
                                               float* __restrict__ out) {
    const int b  = blockIdx.x >> 7;         // / (N_/64 = 128)
    const int rb = blockIdx.x & 127;        // row-block within b
    const int t  = threadIdx.x;
    const int q  = t & 31;                  // float4 column 0..31 (r = q*4..q*4+3)
    const int rp = t >> 5;                  // 0..7

    const float4 val = reinterpret_cast<const float4*>(y)[b * (R_ / 4) + q];
    float4* out4 = reinterpret_cast<float4*>(out)
                   + ((size_t)b * N_ + (size_t)rb * 64) * (R_ / 4);

    #pragma unroll
    for (int n = rp; n < 64; n += 8)
        out4[(size_t)n * (R_ / 4) + q] = val;
}

extern "C" void kernel_launch(void* const* d_in, const int* in_sizes, int n_in,
                              void* d_out, int out_size, void* d_ws, size_t ws_size,
                              hipStream_t stream) {
    const float* x    = (const float*)d_in[0];
    const float* W    = (const float*)d_in[1];
    const float* perm = (const float*)d_in[2];
    float* out = (float*)d_out;

    // Pick chunk count that fits the workspace (partials + y), deterministic in ws_size.
    int chunks = 64;
    while (chunks > 8 &&
           (size_t)(B_ * chunks * D_ + B_ * R_) * sizeof(float) > ws_size)
        chunks >>= 1;

    float* partials = (float*)d_ws;
    float* y        = partials + (size_t)B_ * chunks * D_;

    k_reduce<<<dim3(B_ * chunks), dim3(512), 0, stream>>>(x, partials, chunks);
    k_proj  <<<dim3(B_),          dim3(128), 0, stream>>>(partials, W, perm, y, chunks);
    k_bcast <<<dim3(B_ * (N_ / 64)), dim3(256), 0, stream>>>(y, out);
}

// Round 2
// 42.527 us; speedup vs baseline: 2.6067x; 2.6067x over previous
//
#include <hip/hip_runtime.h>

// Problem constants: x (8, 8192, 512) f32, W (512,128) f32, perm (128,) f32
#define B_ 8
#define N_ 8192
#define D_ 512
#define R_ 128

// Kernel 1: per-chunk column sums of x over the sequence axis.
// grid = B_*chunks blocks, 512 threads. Threads 0..127 cover d in float4 quads,
// 4 row-parallel groups (rp) combined through LDS at the end.
__global__ __launch_bounds__(512) void k_reduce(const float* __restrict__ x,
                                                float* __restrict__ partials,
                                                int chunks) {
    const int rows  = N_ / chunks;          // rows per chunk
    const int b     = blockIdx.x / chunks;
    const int chunk = blockIdx.x % chunks;
    const int t  = threadIdx.x;
    const int dq = t & 127;                 // d-quad index: d = dq*4 .. dq*4+3
    const int rp = t >> 7;                  // row-parallel group 0..3

    const float4* x4 = reinterpret_cast<const float4*>(x)
                       + ((size_t)b * N_ + (size_t)chunk * rows) * (D_ / 4);

    float4 acc = make_float4(0.f, 0.f, 0.f, 0.f);
    for (int n = rp; n < rows; n += 4) {
        float4 v = x4[(size_t)n * (D_ / 4) + dq];
        acc.x += v.x; acc.y += v.y; acc.z += v.z; acc.w += v.w;
    }

    __shared__ float4 s[512];
    s[t] = acc;
    __syncthreads();
    if (rp == 0) {
        float4 a1 = s[dq + 128], a2 = s[dq + 256], a3 = s[dq + 384];
        float4 r;
        r.x = (acc.x + a1.x) + (a2.x + a3.x);
        r.y = (acc.y + a1.y) + (a2.y + a3.y);
        r.z = (acc.z + a1.z) + (a2.z + a3.z);
        r.w = (acc.w + a1.w) + (a2.w + a3.w);
        reinterpret_cast<float4*>(partials)[(size_t)(b * chunks + chunk) * 128 + dq] = r;
    }
}

// Kernel 2: reduce chunk partials -> xbar (mean), project through W, scale by perm.
// grid = B_ blocks, 512 threads. Phase 1: one d per thread, coalesced parallel
// chunk-reduce. Phase 2: 4 groups x 128 channels, LDS tree combine.
__global__ __launch_bounds__(512) void k_proj(const float* __restrict__ partials,
                                              const float* __restrict__ W,
                                              const float* __restrict__ perm,
                                              float* __restrict__ y,
                                              int chunks) {
    const int b = blockIdx.x;
    const int t = threadIdx.x;              // 0..511
    __shared__ float xbar[D_];
    __shared__ float red[512];

    // Phase 1: xbar[d=t] = mean over n == (sum over chunk partials) / N
    {
        const float* p = partials + (size_t)b * chunks * D_ + t;
        float s = 0.f;
        #pragma unroll 8
        for (int c = 0; c < chunks; ++c)
            s += p[(size_t)c * D_];
        xbar[t] = s * (1.0f / (float)N_);
    }
    __syncthreads();

    // Phase 2: partial dot over 128 d's per group, for channel r = t & 127.
    const int r = t & 127;
    const int g = t >> 7;                   // 0..3
    float acc = 0.f;
    #pragma unroll 8
    for (int d0 = 0; d0 < 128; ++d0) {
        const int d = g * 128 + d0;
        acc = fmaf(xbar[d], W[(size_t)d * R_ + r], acc);
    }
    red[t] = acc;
    __syncthreads();
    if (g == 0) {
        float v = ((red[r] + red[r + 128]) + (red[r + 256] + red[r + 384]));
        y[b * R_ + r] = v * perm[r];
    }
}

// Kernel 3: broadcast y[b, :] to out[b, n, :] for all n. Coalesced float4 stores.
// grid = B_ * (N_/64) = 1024 blocks, 256 threads; each block writes 64 rows.
__global__ __launch_bounds__(256) void k_bcast(const float* __restrict__ y,
                                               float* __restrict__ out) {
    const int b  = blockIdx.x >> 7;         // / (N_/64 = 128)
    const int rb = blockIdx.x & 127;        // row-block within b
    const int t  = threadIdx.x;
    const int q  = t & 31;                  // float4 column 0..31
    const int rp = t >> 5;                  // 0..7

    const float4 val = reinterpret_cast<const float4*>(y)[b * (R_ / 4) + q];
    float4* out4 = reinterpret_cast<float4*>(out)
                   + ((size_t)b * N_ + (size_t)rb * 64) * (R_ / 4);

    #pragma unroll
    for (int n = rp; n < 64; n += 8)
        out4[(size_t)n * (R_ / 4) + q] = val;
}

extern "C" void kernel_launch(void* const* d_in, const int* in_sizes, int n_in,
                              void* d_out, int out_size, void* d_ws, size_t ws_size,
                              hipStream_t stream) {
    const float* x    = (const float*)d_in[0];
    const float* W    = (const float*)d_in[1];
    const float* perm = (const float*)d_in[2];
    float* out = (float*)d_out;

    // Pick chunk count that fits the workspace (partials + y), deterministic in ws_size.
    int chunks = 64;
    while (chunks > 8 &&
           (size_t)(B_ * chunks * D_ + B_ * R_) * sizeof(float) > ws_size)
        chunks >>= 1;

    float* partials = (float*)d_ws;
    float* y        = partials + (size_t)B_ * chunks * D_;

    k_reduce<<<dim3(B_ * chunks), dim3(512), 0, stream>>>(x, partials, chunks);
    k_proj  <<<dim3(B_),          dim3(512), 0, stream>>>(partials, W, perm, y, chunks);
    k_bcast <<<dim3(B_ * (N_ / 64)), dim3(256), 0, stream>>>(y, out);
}

// Round 3
// 37.379 us; speedup vs baseline: 2.9657x; 1.1377x over previous
//
#include <hip/hip_runtime.h>

// Problem constants: x (8, 8192, 512) f32, W (512,128) f32, perm (128,) f32
#define B_ 8
#define N_ 8192
#define D_ 512
#define R_ 128

// Kernel 1: per-chunk column-sum of x over seq axis, then project the chunk
// sum through W in-block (W is L2-resident; the dot hides under the HBM
// stream). Emits partial_y[b][chunk][R_] only (256 KB total).
// grid = B_*chunks, 512 threads.
__global__ __launch_bounds__(512) void k_reduce_proj(const float* __restrict__ x,
                                                     const float* __restrict__ W,
                                                     float* __restrict__ partial_y,
                                                     int chunks) {
    const int rows  = N_ / chunks;
    const int b     = blockIdx.x / chunks;
    const int chunk = blockIdx.x % chunks;
    const int t  = threadIdx.x;
    const int dq = t & 127;                 // float4 column over d
    const int rp = t >> 7;                  // row-parallel group 0..3

    const float4* x4 = reinterpret_cast<const float4*>(x)
                       + ((size_t)b * N_ + (size_t)chunk * rows) * (D_ / 4);

    float4 acc = make_float4(0.f, 0.f, 0.f, 0.f);
    for (int n = rp; n < rows; n += 4) {
        float4 v = x4[(size_t)n * (D_ / 4) + dq];
        acc.x += v.x; acc.y += v.y; acc.z += v.z; acc.w += v.w;
    }

    __shared__ float4 s[512];
    __shared__ float  xs[D_];               // per-chunk column sums
    __shared__ float  red[512];

    s[t] = acc;
    __syncthreads();
    if (rp == 0) {
        float4 a1 = s[dq + 128], a2 = s[dq + 256], a3 = s[dq + 384];
        float4 r;
        r.x = (acc.x + a1.x) + (a2.x + a3.x);
        r.y = (acc.y + a1.y) + (a2.y + a3.y);
        r.z = (acc.z + a1.z) + (a2.z + a3.z);
        r.w = (acc.w + a1.w) + (a2.w + a3.w);
        reinterpret_cast<float4*>(xs)[dq] = r;
    }
    __syncthreads();

    // Project: 4 groups x 128 channels; group g covers d = g*128 .. g*128+127.
    const int r128 = t & 127;
    const int g    = t >> 7;
    float accd = 0.f;
    #pragma unroll 8
    for (int d0 = 0; d0 < 128; ++d0) {
        const int d = g * 128 + d0;
        accd = fmaf(xs[d], W[(size_t)d * R_ + r128], accd);
    }
    red[t] = accd;
    __syncthreads();
    if (g == 0) {
        float v = (red[r128] + red[r128 + 128]) + (red[r128 + 256] + red[r128 + 384]);
        partial_y[((size_t)(b * chunks + chunk)) * R_ + r128] = v;
    }
}

// Kernel 2: sum the chunk projections (L2-resident), scale by perm/N, and
// broadcast-write 64 output rows per block. grid = B_*(N_/64) = 1024, 256 thr.
__global__ __launch_bounds__(256) void k_sumbcast(const float* __restrict__ partial_y,
                                                  const float* __restrict__ perm,
                                                  float* __restrict__ out,
                                                  int chunks) {
    const int b  = blockIdx.x >> 7;         // / 128 row-blocks
    const int rb = blockIdx.x & 127;
    const int t  = threadIdx.x;
    const int r    = t & 127;
    const int half = t >> 7;                // 0..1 split over chunks

    __shared__ float red[256];
    __shared__ float yv[R_];

    const int ch = chunks >> 1;
    const float* p = partial_y + ((size_t)b * chunks + (size_t)half * ch) * R_ + r;
    float s = 0.f;
    #pragma unroll 8
    for (int c = 0; c < ch; ++c)
        s += p[(size_t)c * R_];
    red[t] = s;
    __syncthreads();
    if (half == 0)
        yv[r] = (red[r] + red[r + 128]) * perm[r] * (1.0f / (float)N_);
    __syncthreads();

    const int q  = t & 31;                  // float4 column 0..31
    const int rp = t >> 5;                  // 0..7
    const float4 val = reinterpret_cast<const float4*>(yv)[q];
    float4* out4 = reinterpret_cast<float4*>(out)
                   + ((size_t)b * N_ + (size_t)rb * 64) * (R_ / 4);
    #pragma unroll
    for (int n = rp; n < 64; n += 8)
        out4[(size_t)n * (R_ / 4) + q] = val;
}

extern "C" void kernel_launch(void* const* d_in, const int* in_sizes, int n_in,
                              void* d_out, int out_size, void* d_ws, size_t ws_size,
                              hipStream_t stream) {
    const float* x    = (const float*)d_in[0];
    const float* W    = (const float*)d_in[1];
    const float* perm = (const float*)d_in[2];
    float* out = (float*)d_out;

    int chunks = 64;
    while (chunks > 2 &&
           (size_t)(B_ * chunks * R_) * sizeof(float) > ws_size)
        chunks >>= 1;

    float* partial_y = (float*)d_ws;

    k_reduce_proj<<<dim3(B_ * chunks), dim3(512), 0, stream>>>(x, W, partial_y, chunks);
    k_sumbcast  <<<dim3(B_ * (N_ / 64)), dim3(256), 0, stream>>>(partial_y, perm, out, chunks);
}